// Round 5
// baseline (7801.027 us; speedup 1.0000x reference)
//
#include <hip/hip_runtime.h>
#include <hip/hip_bf16.h>
#include <math.h>

// Problem constants (from reference setup_inputs)
#define BB 4
#define SS 512
#define HH 2048
#define EE 16
#define DD 128
#define GH 2048           // E*D
#define G3 6144           // 3*GH
#define NTOK 2048         // B*S

#define LSTR 132          // LDS leading-dim pad for 128-wide tiles

// ---------------- GEMM 1: C[M,N] = A[M,K] * B[N,K]^T  (both K-major) --------
// xi = x @ w_ih^T.  M=2048, N=6144, K=2048. Tile 128x128, BK=8, 8x8/thread.
__global__ __launch_bounds__(256) void gemm_abt(const float* __restrict__ A,
                                                const float* __restrict__ B,
                                                float* __restrict__ C,
                                                int M, int N, int K) {
  __shared__ float As[8][LSTR];
  __shared__ float Bs[8][LSTR];
  const int bm = blockIdx.y * 128, bn = blockIdx.x * 128;
  const int tid = threadIdx.x;
  const int lm = tid >> 1;          // 0..127 row within tile
  const int kh = (tid & 1) * 4;     // 0 or 4
  const int tx = tid & 15, ty = tid >> 4;
  float acc[8][8] = {};
  const float* Arow = A + (size_t)(bm + lm) * K + kh;
  const float* Brow = B + (size_t)(bn + lm) * K + kh;
  for (int k0 = 0; k0 < K; k0 += 8) {
    float4 av = *(const float4*)(Arow + k0);
    float4 bv = *(const float4*)(Brow + k0);
    As[kh + 0][lm] = av.x; As[kh + 1][lm] = av.y; As[kh + 2][lm] = av.z; As[kh + 3][lm] = av.w;
    Bs[kh + 0][lm] = bv.x; Bs[kh + 1][lm] = bv.y; Bs[kh + 2][lm] = bv.z; Bs[kh + 3][lm] = bv.w;
    __syncthreads();
#pragma unroll
    for (int kk = 0; kk < 8; ++kk) {
      float a8[8], b8[8];
      *(float4*)(a8)     = *(const float4*)(&As[kk][ty * 8]);
      *(float4*)(a8 + 4) = *(const float4*)(&As[kk][ty * 8 + 4]);
      *(float4*)(b8)     = *(const float4*)(&Bs[kk][tx * 8]);
      *(float4*)(b8 + 4) = *(const float4*)(&Bs[kk][tx * 8 + 4]);
#pragma unroll
      for (int i = 0; i < 8; ++i)
#pragma unroll
        for (int j = 0; j < 8; ++j) acc[i][j] = fmaf(a8[i], b8[j], acc[i][j]);
    }
    __syncthreads();
  }
#pragma unroll
  for (int i = 0; i < 8; ++i) {
    float4 v0 = {acc[i][0], acc[i][1], acc[i][2], acc[i][3]};
    float4 v1 = {acc[i][4], acc[i][5], acc[i][6], acc[i][7]};
    float* crow = C + (size_t)(bm + ty * 8 + i) * N + bn + tx * 8;
    *(float4*)(crow)     = v0;
    *(float4*)(crow + 4) = v1;
  }
}

// ---------------- GEMM 2: C[M,N] = A[M,K] * B[K,N] ---------------------------
// expression_logits = x @ w_expr. M=2048, N=2048, K=2048.
__global__ __launch_bounds__(256) void gemm_ab(const float* __restrict__ A,
                                               const float* __restrict__ B,
                                               float* __restrict__ C,
                                               int M, int N, int K) {
  __shared__ float As[8][LSTR];
  __shared__ float Bs[8][LSTR];
  const int bm = blockIdx.y * 128, bn = blockIdx.x * 128;
  const int tid = threadIdx.x;
  const int lm = tid >> 1;
  const int kh = (tid & 1) * 4;
  const int bk = tid >> 5;          // 0..7
  const int bn4 = (tid & 31) * 4;   // 0..124
  const int tx = tid & 15, ty = tid >> 4;
  float acc[8][8] = {};
  const float* Arow = A + (size_t)(bm + lm) * K + kh;
  for (int k0 = 0; k0 < K; k0 += 8) {
    float4 av = *(const float4*)(Arow + k0);
    float4 bv = *(const float4*)(B + (size_t)(k0 + bk) * N + bn + bn4);
    As[kh + 0][lm] = av.x; As[kh + 1][lm] = av.y; As[kh + 2][lm] = av.z; As[kh + 3][lm] = av.w;
    *(float4*)(&Bs[bk][bn4]) = bv;
    __syncthreads();
#pragma unroll
    for (int kk = 0; kk < 8; ++kk) {
      float a8[8], b8[8];
      *(float4*)(a8)     = *(const float4*)(&As[kk][ty * 8]);
      *(float4*)(a8 + 4) = *(const float4*)(&As[kk][ty * 8 + 4]);
      *(float4*)(b8)     = *(const float4*)(&Bs[kk][tx * 8]);
      *(float4*)(b8 + 4) = *(const float4*)(&Bs[kk][tx * 8 + 4]);
#pragma unroll
      for (int i = 0; i < 8; ++i)
#pragma unroll
        for (int j = 0; j < 8; ++j) acc[i][j] = fmaf(a8[i], b8[j], acc[i][j]);
    }
    __syncthreads();
  }
#pragma unroll
  for (int i = 0; i < 8; ++i) {
    float4 v0 = {acc[i][0], acc[i][1], acc[i][2], acc[i][3]};
    float4 v1 = {acc[i][4], acc[i][5], acc[i][6], acc[i][7]};
    float* crow = C + (size_t)(bm + ty * 8 + i) * N + bn + tx * 8;
    *(float4*)(crow)     = v0;
    *(float4*)(crow + 4) = v1;
  }
}

// ---------------- A^T*A loss: sum over (i,j) of (A^T A - I)^2 ---------------
__global__ __launch_bounds__(256) void ata_loss(const float* __restrict__ A,
                                                float* __restrict__ el_accum,
                                                int N, int K) {
  __shared__ float As[8][LSTR];
  __shared__ float Bs[8][LSTR];
  __shared__ float red[256];
  const int bi = blockIdx.y * 128, bj = blockIdx.x * 128;
  const int tid = threadIdx.x;
  const int bk = tid >> 5;
  const int bn4 = (tid & 31) * 4;
  const int tx = tid & 15, ty = tid >> 4;
  float acc[8][8] = {};
  for (int k0 = 0; k0 < K; k0 += 8) {
    float4 av = *(const float4*)(A + (size_t)(k0 + bk) * N + bi + bn4);
    float4 bv = *(const float4*)(A + (size_t)(k0 + bk) * N + bj + bn4);
    *(float4*)(&As[bk][bn4]) = av;
    *(float4*)(&Bs[bk][bn4]) = bv;
    __syncthreads();
#pragma unroll
    for (int kk = 0; kk < 8; ++kk) {
      float a8[8], b8[8];
      *(float4*)(a8)     = *(const float4*)(&As[kk][ty * 8]);
      *(float4*)(a8 + 4) = *(const float4*)(&As[kk][ty * 8 + 4]);
      *(float4*)(b8)     = *(const float4*)(&Bs[kk][tx * 8]);
      *(float4*)(b8 + 4) = *(const float4*)(&Bs[kk][tx * 8 + 4]);
#pragma unroll
      for (int i = 0; i < 8; ++i)
#pragma unroll
        for (int j = 0; j < 8; ++j) acc[i][j] = fmaf(a8[i], b8[j], acc[i][j]);
    }
    __syncthreads();
  }
  float local = 0.f;
#pragma unroll
  for (int i = 0; i < 8; ++i) {
#pragma unroll
    for (int j = 0; j < 8; ++j) {
      int gi = bi + ty * 8 + i, gj = bj + tx * 8 + j;
      float d = acc[i][j] - ((gi == gj) ? 1.0f : 0.0f);
      local += d * d;
    }
  }
  red[tid] = local;
  __syncthreads();
  for (int s = 128; s > 0; s >>= 1) {
    if (tid < s) red[tid] += red[tid + s];
    __syncthreads();
  }
  if (tid == 0) atomicAdd(el_accum, red[0]);
}

// ---------------- persistent GRU: barrier-free self-validating dataflow ------
__device__ inline float wred64(float v) {
#pragma unroll
  for (int o = 32; o; o >>= 1) v += __shfl_xor(v, o);
  return v;
}

// 256 blocks x 512 threads, cooperative (co-residency guaranteed).
// Wave w of block bk owns column j = bk*8+w; its 3 w_hh rows live in
// registers (lane-strided k).
// Exchange: NO barrier, NO flags. Each h value travels as a packed uint64
// (step_tag<<32 | float_bits) through hx[] via relaxed agent atomics
// (write-through to L3, the path proven in R3/R4). Consumers load the
// packed word and accept iff tag == s+1 — validity rides in the same atom,
// so there is no flag/data ordering hazard and no producer-side drain.
// Tag equality is poison-safe (0xAAAAAAAA != s+1) and monotone within a run.
// Deadlock-free: co-resident blocks produce unconditionally each step.
__global__ __launch_bounds__(512, 2) void gru_persistent(
    const float* __restrict__ xi,    // [B,S,3GH]
    const float* __restrict__ w_hh,  // [3GH,GH]
    const float* __restrict__ hn,    // [B,GH]
    float* __restrict__ hs,          // [B,S,GH] (plain stores, read after kernel)
    unsigned long long* __restrict__ hx) {  // [GH*4] packed (tag|bits)
  __shared__ __align__(16) float hsm[BB * GH];  // [k][b] interleaved, 32 KB
  const int tid = threadIdx.x;
  const int wave = tid >> 6, lane = tid & 63;
  const int j = blockIdx.x * 8 + wave;

  // weights -> registers (lane-strided k): reg c <-> k = c*64+lane
  float wgr[32], wgz[32], wgn[32];
  {
    const float* pr = w_hh + (size_t)j * GH;
    const float* pz = w_hh + (size_t)(GH + j) * GH;
    const float* pn = w_hh + (size_t)(2 * GH + j) * GH;
#pragma unroll
    for (int c = 0; c < 32; ++c) {
      int k = c * 64 + lane;
      wgr[c] = pr[k]; wgz[c] = pz[k]; wgn[c] = pn[k];
    }
  }
  // initial h from hn, batch-interleaved
#pragma unroll
  for (int i = 0; i < 4; ++i) {
    int k = tid + i * 512;
    float4 v;
    v.x = hn[0 * GH + k]; v.y = hn[1 * GH + k];
    v.z = hn[2 * GH + k]; v.w = hn[3 * GH + k];
    *(float4*)(&hsm[k * 4]) = v;
  }
  __syncthreads();

  for (int s = 0; s < SS; ++s) {
    // prefetch xi gate inputs early (latency hidden behind the dot loop)
    float xr = 0.f, xz = 0.f, xn_ = 0.f;
    if (lane < BB) {
      const float* xrow = xi + ((size_t)(lane * SS + s)) * G3;
      xr  = xrow[j];
      xz  = xrow[GH + j];
      xn_ = xrow[2 * GH + j];
    }

    float ar[BB] = {}, az[BB] = {}, an[BB] = {};
#pragma unroll
    for (int c = 0; c < 32; ++c) {
      float4 h4 = *(const float4*)(&hsm[(c * 64 + lane) * 4]);
      float w_r = wgr[c], w_z = wgz[c], w_n = wgn[c];
      ar[0] = fmaf(w_r, h4.x, ar[0]); az[0] = fmaf(w_z, h4.x, az[0]); an[0] = fmaf(w_n, h4.x, an[0]);
      ar[1] = fmaf(w_r, h4.y, ar[1]); az[1] = fmaf(w_z, h4.y, az[1]); an[1] = fmaf(w_n, h4.y, an[1]);
      ar[2] = fmaf(w_r, h4.z, ar[2]); az[2] = fmaf(w_z, h4.z, az[2]); an[2] = fmaf(w_n, h4.z, an[2]);
      ar[3] = fmaf(w_r, h4.w, ar[3]); az[3] = fmaf(w_z, h4.w, az[3]); an[3] = fmaf(w_n, h4.w, an[3]);
    }
#pragma unroll
    for (int b = 0; b < BB; ++b) { ar[b] = wred64(ar[b]); az[b] = wred64(az[b]); an[b] = wred64(an[b]); }

    if (lane < BB) {
      const int b = lane;
      float r = 1.0f / (1.0f + expf(-(xr + ar[b])));
      float z = 1.0f / (1.0f + expf(-(xz + az[b])));
      float n = tanhf(xn_ + r * an[b]);
      float hp = hsm[j * 4 + b];
      float hv = (1.0f - z) * n + z * hp;
      // plain store for downstream kernels (flushed at kernel end)
      hs[((size_t)(b * SS + s)) * GH + j] = hv;
      // packed (tag | bits) exchange word: write-through to L3
      unsigned long long pkt =
          ((unsigned long long)(unsigned)(s + 1) << 32) |
          (unsigned long long)__float_as_uint(hv);
      __hip_atomic_store(&hx[(size_t)j * 4 + b], pkt,
                         __ATOMIC_RELAXED, __HIP_MEMORY_SCOPE_AGENT);
    }

    if (s + 1 < SS) {
      __syncthreads();  // all this block's dot-reads of hsm are done
      // restage h(s) from hx: thread t owns columns c*512+t, c=0..3.
      const unsigned want = (unsigned)(s + 1);
      unsigned pending = 0xFu;
      float4 cols[4];
      do {
#pragma unroll
        for (int c = 0; c < 4; ++c) {
          if (pending & (1u << c)) {
            const size_t base = (size_t)(c * 512 + tid) * 4;
            unsigned long long u0 = __hip_atomic_load(&hx[base + 0], __ATOMIC_RELAXED, __HIP_MEMORY_SCOPE_AGENT);
            unsigned long long u1 = __hip_atomic_load(&hx[base + 1], __ATOMIC_RELAXED, __HIP_MEMORY_SCOPE_AGENT);
            unsigned long long u2 = __hip_atomic_load(&hx[base + 2], __ATOMIC_RELAXED, __HIP_MEMORY_SCOPE_AGENT);
            unsigned long long u3 = __hip_atomic_load(&hx[base + 3], __ATOMIC_RELAXED, __HIP_MEMORY_SCOPE_AGENT);
            bool ok = ((unsigned)(u0 >> 32) == want) & ((unsigned)(u1 >> 32) == want) &
                      ((unsigned)(u2 >> 32) == want) & ((unsigned)(u3 >> 32) == want);
            if (ok) {
              cols[c].x = __uint_as_float((unsigned)u0);
              cols[c].y = __uint_as_float((unsigned)u1);
              cols[c].z = __uint_as_float((unsigned)u2);
              cols[c].w = __uint_as_float((unsigned)u3);
              pending &= ~(1u << c);
            }
          }
        }
        if (pending) __builtin_amdgcn_s_sleep(2);
      } while (pending);
#pragma unroll
      for (int c = 0; c < 4; ++c)
        *(float4*)(&hsm[(size_t)(c * 512 + tid) * 4]) = cols[c];
      __syncthreads();  // hsm fully restaged before next dot
    }
  }
}

// ---------------- per-token: normalize, gram/speciality, cosine --------------
__device__ inline float red16(float v) {
#pragma unroll
  for (int o = 8; o; o >>= 1) v += __shfl_xor(v, o);
  return v;
}

__global__ __launch_bounds__(256) void token_kernel(const float* __restrict__ hs,
                                                    const float* __restrict__ expr,
                                                    float* __restrict__ cos_out,
                                                    float* __restrict__ sp_accum) {
  __shared__ float routn[EE * 132];
  __shared__ float rowc[EE];
  const int t = blockIdx.x;
  const int tid = threadIdx.x;
  const int e = tid >> 4, sub = tid & 15;

  const float* rrow = hs + (size_t)t * GH + e * DD + sub * 8;
  float rv[8];
#pragma unroll
  for (int i = 0; i < 8; ++i) rv[i] = rrow[i];
  float ss = 0.f;
#pragma unroll
  for (int i = 0; i < 8; ++i) ss += rv[i] * rv[i];
  ss = red16(ss);
  float inv = 1.0f / fmaxf(sqrtf(ss), 1e-12f);
#pragma unroll
  for (int i = 0; i < 8; ++i) {
    rv[i] *= inv;
    routn[e * 132 + sub * 8 + i] = rv[i];
  }

  const float* erow = expr + (size_t)t * GH + e * DD + sub * 8;
  float en2 = 0.f, dot = 0.f;
#pragma unroll
  for (int i = 0; i < 8; ++i) {
    float ev = erow[i];
    en2 += ev * ev;
    dot += ev * rv[i];
  }
  en2 = red16(en2);
  dot = red16(dot);
  if (sub == 0) {
    float cosv = dot / fmaxf(sqrtf(en2), 1e-8f);
    cos_out[t * EE + e] = 1.0f - cosv;
  }
  __syncthreads();

  const int f = sub;
  float g = 0.f;
#pragma unroll
  for (int d = 0; d < DD; ++d)
    g = fmaf(routn[e * 132 + d], routn[f * 132 + d], g);
  float diff = g - ((e == f) ? 1.0f : 0.0f);
  float rowsum = red16(diff * diff);
  if (f == 0) {
    float nrm = fmaxf(sqrtf(rowsum), 1e-12f);
    rowc[e] = rowsum / (nrm * nrm);
  }
  __syncthreads();
  if (tid == 0) {
    float tok = 0.f;
#pragma unroll
    for (int i = 0; i < EE; ++i) tok += rowc[i];
    atomicAdd(sp_accum, tok);
  }
}

// ---------------- final: top-2 + softmax + EMA adjust + hn copy + scalars ----
__global__ __launch_bounds__(256) void final_kernel(const float* __restrict__ hs,
                                                    const float* __restrict__ cos_out,
                                                    const float* __restrict__ ema,
                                                    const float* __restrict__ accum,
                                                    float* __restrict__ out_mult,
                                                    float* __restrict__ out_sel,
                                                    float* __restrict__ out_hn,
                                                    float* __restrict__ out_sp,
                                                    float* __restrict__ out_el) {
  const int gtid = blockIdx.x * 256 + threadIdx.x;
  if (gtid < BB * GH) {
    int b = gtid / GH, jj = gtid % GH;
    out_hn[gtid] = hs[((size_t)(b * SS + SS - 1)) * GH + jj];
  }
  if (gtid < NTOK) {
    float sp = accum[0] / (float)NTOK;
    float scale = 1.0f + sp;
    float dv[EE];
#pragma unroll
    for (int e = 0; e < EE; ++e) dv[e] = cos_out[gtid * EE + e] * scale;
    int i0 = 0; float v0 = dv[0];
#pragma unroll
    for (int e = 1; e < EE; ++e) { if (dv[e] > v0) { v0 = dv[e]; i0 = e; } }
    int i1 = -1; float v1 = -1e30f;
#pragma unroll
    for (int e = 0; e < EE; ++e) { if (e != i0 && dv[e] > v1) { v1 = dv[e]; i1 = e; } }
    float ex = expf(v1 - v0);
    float den = 1.0f + ex;
    float m0 = 1.0f / den, m1 = ex / den;
    float total = 0.f;
#pragma unroll
    for (int e = 0; e < EE; ++e) total += ema[e];
    float a0 = 0.f, a1 = 0.f;
    if (total > 0.f) {
      float invt = 1.0f / fmaxf(total, 1e-12f);
      a0 = ema[i0] * invt * 0.01f * (float)EE;
      a1 = ema[i1] * invt * 0.01f * (float)EE;
    }
    out_mult[gtid * 2 + 0] = m0 - a0;
    out_mult[gtid * 2 + 1] = m1 - a1;
    out_sel[gtid * 2 + 0] = (float)i0;
    out_sel[gtid * 2 + 1] = (float)i1;
  }
  if (gtid == 0) {
    out_sp[0] = accum[0] / (float)NTOK;
    out_el[0] = accum[1] / (float)(GH * GH);
  }
}

extern "C" void kernel_launch(void* const* d_in, const int* in_sizes, int n_in,
                              void* d_out, int out_size, void* d_ws, size_t ws_size,
                              hipStream_t stream) {
  const float* x      = (const float*)d_in[0];  // [B,S,H]
  const float* hn     = (const float*)d_in[1];  // [1,B,GH]
  const float* w_ih   = (const float*)d_in[2];  // [3GH,H]
  const float* w_hh   = (const float*)d_in[3];  // [3GH,GH]
  const float* w_expr = (const float*)d_in[4];  // [H,GH]
  const float* ema    = (const float*)d_in[5];  // [E]
  float* out = (float*)d_out;

  float* out_mult = out;                 // 4096
  float* out_sel  = out + 4096;          // 4096
  float* out_expr = out + 8192;          // 4194304
  float* out_hn   = out + 4202496;       // 8192
  float* out_sp   = out + 4210688;       // 1
  float* out_cos  = out + 4210689;       // 32768
  float* out_el   = out + 4243457;       // 1

  float* ws = (float*)d_ws;
  float* xi    = ws;                     // [B,S,3GH] 12,582,912 floats
  float* hs    = ws + 12582912;          // [B,S,GH]   4,194,304 floats
  float* accum = ws + 16777216;          // [0]=sp_sum, [1]=el_sum
  unsigned long long* hx = (unsigned long long*)(ws + 16777224);  // GH*4 packed words (8B-aligned)

  hipMemsetAsync(accum, 0, 2 * sizeof(float), stream);
  // hx needs NO init: consumers accept only tag == s+1 (poison 0xAAAAAAAA never matches)

  // xi = x @ w_ih^T   (M=2048, N=6144, K=2048)
  gemm_abt<<<dim3(G3 / 128, NTOK / 128), 256, 0, stream>>>(x, w_ih, xi, NTOK, G3, HH);

  // expression_logits = x @ w_expr  -> straight to d_out
  gemm_ab<<<dim3(GH / 128, NTOK / 128), 256, 0, stream>>>(x, w_expr, out_expr, NTOK, GH, HH);

  // GRU recurrence: persistent cooperative kernel, barrier-free dataflow
  {
    void* args[] = {(void*)&xi, (void*)&w_hh, (void*)&hn, (void*)&hs, (void*)&hx};
    hipLaunchCooperativeKernel((void*)gru_persistent, dim3(256), dim3(512),
                               args, 0, stream);
  }

  // expression orthogonality loss
  ata_loss<<<dim3(GH / 128, GH / 128), 256, 0, stream>>>(w_expr, accum + 1, GH, HH);

  // per-token speciality + cosine
  token_kernel<<<NTOK, 256, 0, stream>>>(hs, out_expr, out_cos, accum);

  // final routing + copies + scalars
  final_kernel<<<(BB * GH + 255) / 256, 256, 0, stream>>>(hs, out_cos, ema, accum,
                                                          out_mult, out_sel, out_hn,
                                                          out_sp, out_el);
}

// Round 6
// 3989.577 us; speedup vs baseline: 1.9554x; 1.9554x over previous
//
#include <hip/hip_runtime.h>
#include <hip/hip_bf16.h>
#include <math.h>

// Problem constants (from reference setup_inputs)
#define BB 4
#define SS 512
#define HH 2048
#define EE 16
#define DD 128
#define GH 2048           // E*D
#define G3 6144           // 3*GH
#define NTOK 2048         // B*S

#define LSTR 132          // LDS leading-dim pad for 128-wide fp32 tiles
#define FPAD 32           // flag padding: one flag per 128 B
#define KS 40             // bf16 LDS row stride in shorts (32 + 8 pad)

typedef __attribute__((ext_vector_type(8))) short short8;   // 8 bf16 = 4 VGPR
typedef __attribute__((ext_vector_type(4))) float f32x4;    // MFMA C/D

// ---------------- GEMM 1 (fp32): C[M,N] = A[M,K] * B[N,K]^T ------------------
// xi = x @ w_ih^T. Kept fp32: xi feeds the chaotic GRU recurrence (absmax
// 0.0156 from fp32-level seeds implies ~1e4 amplification; bf16 here would
// blow the threshold). Tile 128x128, BK=8, 8x8/thread.
__global__ __launch_bounds__(256) void gemm_abt(const float* __restrict__ A,
                                                const float* __restrict__ B,
                                                float* __restrict__ C,
                                                int M, int N, int K) {
  __shared__ float As[8][LSTR];
  __shared__ float Bs[8][LSTR];
  const int bm = blockIdx.y * 128, bn = blockIdx.x * 128;
  const int tid = threadIdx.x;
  const int lm = tid >> 1;
  const int kh = (tid & 1) * 4;
  const int tx = tid & 15, ty = tid >> 4;
  float acc[8][8] = {};
  const float* Arow = A + (size_t)(bm + lm) * K + kh;
  const float* Brow = B + (size_t)(bn + lm) * K + kh;
  for (int k0 = 0; k0 < K; k0 += 8) {
    float4 av = *(const float4*)(Arow + k0);
    float4 bv = *(const float4*)(Brow + k0);
    As[kh + 0][lm] = av.x; As[kh + 1][lm] = av.y; As[kh + 2][lm] = av.z; As[kh + 3][lm] = av.w;
    Bs[kh + 0][lm] = bv.x; Bs[kh + 1][lm] = bv.y; Bs[kh + 2][lm] = bv.z; Bs[kh + 3][lm] = bv.w;
    __syncthreads();
#pragma unroll
    for (int kk = 0; kk < 8; ++kk) {
      float a8[8], b8[8];
      *(float4*)(a8)     = *(const float4*)(&As[kk][ty * 8]);
      *(float4*)(a8 + 4) = *(const float4*)(&As[kk][ty * 8 + 4]);
      *(float4*)(b8)     = *(const float4*)(&Bs[kk][tx * 8]);
      *(float4*)(b8 + 4) = *(const float4*)(&Bs[kk][tx * 8 + 4]);
#pragma unroll
      for (int i = 0; i < 8; ++i)
#pragma unroll
        for (int j = 0; j < 8; ++j) acc[i][j] = fmaf(a8[i], b8[j], acc[i][j]);
    }
    __syncthreads();
  }
#pragma unroll
  for (int i = 0; i < 8; ++i) {
    float4 v0 = {acc[i][0], acc[i][1], acc[i][2], acc[i][3]};
    float4 v1 = {acc[i][4], acc[i][5], acc[i][6], acc[i][7]};
    float* crow = C + (size_t)(bm + ty * 8 + i) * N + bn + tx * 8;
    *(float4*)(crow)     = v0;
    *(float4*)(crow + 4) = v1;
  }
}

// ---------------- fp32 fallbacks (used only if ws too small) -----------------
__global__ __launch_bounds__(256) void gemm_ab(const float* __restrict__ A,
                                               const float* __restrict__ B,
                                               float* __restrict__ C,
                                               int M, int N, int K) {
  __shared__ float As[8][LSTR];
  __shared__ float Bs[8][LSTR];
  const int bm = blockIdx.y * 128, bn = blockIdx.x * 128;
  const int tid = threadIdx.x;
  const int lm = tid >> 1;
  const int kh = (tid & 1) * 4;
  const int bk = tid >> 5;
  const int bn4 = (tid & 31) * 4;
  const int tx = tid & 15, ty = tid >> 4;
  float acc[8][8] = {};
  const float* Arow = A + (size_t)(bm + lm) * K + kh;
  for (int k0 = 0; k0 < K; k0 += 8) {
    float4 av = *(const float4*)(Arow + k0);
    float4 bv = *(const float4*)(B + (size_t)(k0 + bk) * N + bn + bn4);
    As[kh + 0][lm] = av.x; As[kh + 1][lm] = av.y; As[kh + 2][lm] = av.z; As[kh + 3][lm] = av.w;
    *(float4*)(&Bs[bk][bn4]) = bv;
    __syncthreads();
#pragma unroll
    for (int kk = 0; kk < 8; ++kk) {
      float a8[8], b8[8];
      *(float4*)(a8)     = *(const float4*)(&As[kk][ty * 8]);
      *(float4*)(a8 + 4) = *(const float4*)(&As[kk][ty * 8 + 4]);
      *(float4*)(b8)     = *(const float4*)(&Bs[kk][tx * 8]);
      *(float4*)(b8 + 4) = *(const float4*)(&Bs[kk][tx * 8 + 4]);
#pragma unroll
      for (int i = 0; i < 8; ++i)
#pragma unroll
        for (int j = 0; j < 8; ++j) acc[i][j] = fmaf(a8[i], b8[j], acc[i][j]);
    }
    __syncthreads();
  }
#pragma unroll
  for (int i = 0; i < 8; ++i) {
    float4 v0 = {acc[i][0], acc[i][1], acc[i][2], acc[i][3]};
    float4 v1 = {acc[i][4], acc[i][5], acc[i][6], acc[i][7]};
    float* crow = C + (size_t)(bm + ty * 8 + i) * N + bn + tx * 8;
    *(float4*)(crow)     = v0;
    *(float4*)(crow + 4) = v1;
  }
}

__global__ __launch_bounds__(256) void ata_loss(const float* __restrict__ A,
                                                float* __restrict__ el_accum,
                                                int N, int K) {
  __shared__ float As[8][LSTR];
  __shared__ float Bs[8][LSTR];
  __shared__ float red[256];
  const int bi = blockIdx.y * 128, bj = blockIdx.x * 128;
  const int tid = threadIdx.x;
  const int bk = tid >> 5;
  const int bn4 = (tid & 31) * 4;
  const int tx = tid & 15, ty = tid >> 4;
  float acc[8][8] = {};
  for (int k0 = 0; k0 < K; k0 += 8) {
    float4 av = *(const float4*)(A + (size_t)(k0 + bk) * N + bi + bn4);
    float4 bv = *(const float4*)(A + (size_t)(k0 + bk) * N + bj + bn4);
    *(float4*)(&As[bk][bn4]) = av;
    *(float4*)(&Bs[bk][bn4]) = bv;
    __syncthreads();
#pragma unroll
    for (int kk = 0; kk < 8; ++kk) {
      float a8[8], b8[8];
      *(float4*)(a8)     = *(const float4*)(&As[kk][ty * 8]);
      *(float4*)(a8 + 4) = *(const float4*)(&As[kk][ty * 8 + 4]);
      *(float4*)(b8)     = *(const float4*)(&Bs[kk][tx * 8]);
      *(float4*)(b8 + 4) = *(const float4*)(&Bs[kk][tx * 8 + 4]);
#pragma unroll
      for (int i = 0; i < 8; ++i)
#pragma unroll
        for (int j = 0; j < 8; ++j) acc[i][j] = fmaf(a8[i], b8[j], acc[i][j]);
    }
    __syncthreads();
  }
  float local = 0.f;
#pragma unroll
  for (int i = 0; i < 8; ++i) {
#pragma unroll
    for (int j = 0; j < 8; ++j) {
      int gi = bi + ty * 8 + i, gj = bj + tx * 8 + j;
      float d = acc[i][j] - ((gi == gj) ? 1.0f : 0.0f);
      local += d * d;
    }
  }
  red[tid] = local;
  __syncthreads();
  for (int s = 128; s > 0; s >>= 1) {
    if (tid < s) red[tid] += red[tid + s];
    __syncthreads();
  }
  if (tid == 0) atomicAdd(el_accum, red[0]);
}

// ---------------- split-bf16 helpers -----------------------------------------
__device__ inline void bf16_split(float v, unsigned short& hi, unsigned short& lo) {
  unsigned u = __float_as_uint(v);
  unsigned r = u + 0x7FFFu + ((u >> 16) & 1u);   // RTN-even to bf16
  hi = (unsigned short)(r >> 16);
  float rem = v - __uint_as_float((unsigned)hi << 16);  // exact (Sterbenz)
  lo = (unsigned short)(__float_as_uint(rem) >> 16);    // truncate remainder
}

__global__ __launch_bounds__(256) void split_mat(const float* __restrict__ A,
                                                 unsigned short* __restrict__ Hh,
                                                 unsigned short* __restrict__ Hl,
                                                 int n) {
  int i = blockIdx.x * 256 + threadIdx.x;
  int stride = gridDim.x * 256;
  for (; i < n; i += stride) {
    unsigned short hi, lo;
    bf16_split(A[i], hi, lo);
    Hh[i] = hi; Hl[i] = lo;
  }
}

// w_expr [H][GH] -> transposed split T[GH][H] (hi/lo bf16)
__global__ __launch_bounds__(256) void transpose_split(const float* __restrict__ A,
                                                       unsigned short* __restrict__ Th,
                                                       unsigned short* __restrict__ Tl) {
  __shared__ float tile[64][65];
  const int bx = blockIdx.x * 64, by = blockIdx.y * 64;  // bx: n, by: k
  const int tx = threadIdx.x & 63, ty = threadIdx.x >> 6;
#pragma unroll
  for (int i = 0; i < 16; ++i) {
    int r = ty + i * 4;
    tile[r][tx] = A[(size_t)(by + r) * GH + bx + tx];
  }
  __syncthreads();
#pragma unroll
  for (int i = 0; i < 16; ++i) {
    int r = ty + i * 4;                 // output row n = bx + r; col k = by + tx
    unsigned short hi, lo;
    bf16_split(tile[tx][r], hi, lo);
    Th[(size_t)(bx + r) * HH + by + tx] = hi;
    Tl[(size_t)(bx + r) * HH + by + tx] = lo;
  }
}

// ---------------- split-bf16 MFMA GEMM: C[M,N] = A[M,K]*B[N,K]^T -------------
// A,B given as bf16 (hi,lo); acc = Ah*Bh + Ah*Bl + Al*Bh (drop Al*Bl ~2^-18).
// 128x128 tile, BK=32 (one 16x16x32 MFMA k-step), 4 waves x 64x64 quadrant,
// padded LDS stride (KS=40 shorts) -> <=2-way bank conflicts (free per m136).
__global__ __launch_bounds__(256) void gemm_abt_bf16(
    const unsigned short* __restrict__ Ah, const unsigned short* __restrict__ Al,
    const unsigned short* __restrict__ Bh, const unsigned short* __restrict__ Bl,
    float* __restrict__ C, int M, int N, int K) {
  __shared__ unsigned short Ahs[128 * KS], Als[128 * KS];
  __shared__ unsigned short Bhs[128 * KS], Bls[128 * KS];
  const int tid = threadIdx.x;
  const int wv = tid >> 6, lane = tid & 63;
  const int qr = wv >> 1, qc = wv & 1;
  const int m16 = lane & 15, q = lane >> 4;
  const int bm = blockIdx.y * 128, bn = blockIdx.x * 128;
  const int sr = tid >> 1, sh = (tid & 1) * 16;   // staging: row, k-half
  f32x4 zero = {0.f, 0.f, 0.f, 0.f};
  f32x4 acc[4][4];
#pragma unroll
  for (int i = 0; i < 4; ++i)
#pragma unroll
    for (int j = 0; j < 4; ++j) acc[i][j] = zero;

  for (int k0 = 0; k0 < K; k0 += 32) {
    const size_t ga = (size_t)(bm + sr) * K + k0 + sh;
    const size_t gb = (size_t)(bn + sr) * K + k0 + sh;
    short8 a0 = *(const short8*)(Ah + ga);
    short8 a1 = *(const short8*)(Ah + ga + 8);
    short8 l0 = *(const short8*)(Al + ga);
    short8 l1 = *(const short8*)(Al + ga + 8);
    short8 b0 = *(const short8*)(Bh + gb);
    short8 b1 = *(const short8*)(Bh + gb + 8);
    short8 m0 = *(const short8*)(Bl + gb);
    short8 m1 = *(const short8*)(Bl + gb + 8);
    __syncthreads();   // previous iter's frag reads complete
    *(short8*)&Ahs[sr * KS + sh]     = a0;
    *(short8*)&Ahs[sr * KS + sh + 8] = a1;
    *(short8*)&Als[sr * KS + sh]     = l0;
    *(short8*)&Als[sr * KS + sh + 8] = l1;
    *(short8*)&Bhs[sr * KS + sh]     = b0;
    *(short8*)&Bhs[sr * KS + sh + 8] = b1;
    *(short8*)&Bls[sr * KS + sh]     = m0;
    *(short8*)&Bls[sr * KS + sh + 8] = m1;
    __syncthreads();
    short8 afh[4], afl[4], bfh[4], bfl[4];
#pragma unroll
    for (int t = 0; t < 4; ++t) {
      const int raddr = (qr * 64 + t * 16 + m16) * KS + q * 8;
      const int caddr = (qc * 64 + t * 16 + m16) * KS + q * 8;
      afh[t] = *(const short8*)&Ahs[raddr];
      afl[t] = *(const short8*)&Als[raddr];
      bfh[t] = *(const short8*)&Bhs[caddr];
      bfl[t] = *(const short8*)&Bls[caddr];
    }
#pragma unroll
    for (int tm = 0; tm < 4; ++tm)
#pragma unroll
      for (int tn = 0; tn < 4; ++tn) {
        acc[tm][tn] = __builtin_amdgcn_mfma_f32_16x16x32_bf16(afh[tm], bfh[tn], acc[tm][tn], 0, 0, 0);
        acc[tm][tn] = __builtin_amdgcn_mfma_f32_16x16x32_bf16(afh[tm], bfl[tn], acc[tm][tn], 0, 0, 0);
        acc[tm][tn] = __builtin_amdgcn_mfma_f32_16x16x32_bf16(afl[tm], bfh[tn], acc[tm][tn], 0, 0, 0);
      }
  }
  // C/D layout: col = lane&15, row = (lane>>4)*4 + reg  [m89-verified]
#pragma unroll
  for (int tm = 0; tm < 4; ++tm)
#pragma unroll
    for (int tn = 0; tn < 4; ++tn)
#pragma unroll
      for (int r = 0; r < 4; ++r)
        C[(size_t)(bm + qr * 64 + tm * 16 + q * 4 + r) * N +
          bn + qc * 64 + tn * 16 + m16] = acc[tm][tn][r];
}

// same mainloop, A=B=w_exprT; epilogue reduces (g - I)^2 instead of writing C
__global__ __launch_bounds__(256) void ata_bf16(
    const unsigned short* __restrict__ Th, const unsigned short* __restrict__ Tl,
    float* __restrict__ el_accum, int N, int K) {
  __shared__ unsigned short Ahs[128 * KS], Als[128 * KS];
  __shared__ unsigned short Bhs[128 * KS], Bls[128 * KS];
  __shared__ float red[256];
  const int tid = threadIdx.x;
  const int wv = tid >> 6, lane = tid & 63;
  const int qr = wv >> 1, qc = wv & 1;
  const int m16 = lane & 15, q = lane >> 4;
  const int bi = blockIdx.y * 128, bj = blockIdx.x * 128;
  const int sr = tid >> 1, sh = (tid & 1) * 16;
  f32x4 zero = {0.f, 0.f, 0.f, 0.f};
  f32x4 acc[4][4];
#pragma unroll
  for (int i = 0; i < 4; ++i)
#pragma unroll
    for (int j = 0; j < 4; ++j) acc[i][j] = zero;

  for (int k0 = 0; k0 < K; k0 += 32) {
    const size_t ga = (size_t)(bi + sr) * K + k0 + sh;
    const size_t gb = (size_t)(bj + sr) * K + k0 + sh;
    short8 a0 = *(const short8*)(Th + ga);
    short8 a1 = *(const short8*)(Th + ga + 8);
    short8 l0 = *(const short8*)(Tl + ga);
    short8 l1 = *(const short8*)(Tl + ga + 8);
    short8 b0 = *(const short8*)(Th + gb);
    short8 b1 = *(const short8*)(Th + gb + 8);
    short8 m0 = *(const short8*)(Tl + gb);
    short8 m1 = *(const short8*)(Tl + gb + 8);
    __syncthreads();
    *(short8*)&Ahs[sr * KS + sh]     = a0;
    *(short8*)&Ahs[sr * KS + sh + 8] = a1;
    *(short8*)&Als[sr * KS + sh]     = l0;
    *(short8*)&Als[sr * KS + sh + 8] = l1;
    *(short8*)&Bhs[sr * KS + sh]     = b0;
    *(short8*)&Bhs[sr * KS + sh + 8] = b1;
    *(short8*)&Bls[sr * KS + sh]     = m0;
    *(short8*)&Bls[sr * KS + sh + 8] = m1;
    __syncthreads();
    short8 afh[4], afl[4], bfh[4], bfl[4];
#pragma unroll
    for (int t = 0; t < 4; ++t) {
      const int raddr = (qr * 64 + t * 16 + m16) * KS + q * 8;
      const int caddr = (qc * 64 + t * 16 + m16) * KS + q * 8;
      afh[t] = *(const short8*)&Ahs[raddr];
      afl[t] = *(const short8*)&Als[raddr];
      bfh[t] = *(const short8*)&Bhs[caddr];
      bfl[t] = *(const short8*)&Bls[caddr];
    }
#pragma unroll
    for (int tm = 0; tm < 4; ++tm)
#pragma unroll
      for (int tn = 0; tn < 4; ++tn) {
        acc[tm][tn] = __builtin_amdgcn_mfma_f32_16x16x32_bf16(afh[tm], bfh[tn], acc[tm][tn], 0, 0, 0);
        acc[tm][tn] = __builtin_amdgcn_mfma_f32_16x16x32_bf16(afh[tm], bfl[tn], acc[tm][tn], 0, 0, 0);
        acc[tm][tn] = __builtin_amdgcn_mfma_f32_16x16x32_bf16(afl[tm], bfh[tn], acc[tm][tn], 0, 0, 0);
      }
  }
  float local = 0.f;
#pragma unroll
  for (int tm = 0; tm < 4; ++tm)
#pragma unroll
    for (int tn = 0; tn < 4; ++tn)
#pragma unroll
      for (int r = 0; r < 4; ++r) {
        int gi = bi + qr * 64 + tm * 16 + q * 4 + r;
        int gj = bj + qc * 64 + tn * 16 + m16;
        float d = acc[tm][tn][r] - ((gi == gj) ? 1.0f : 0.0f);
        local += d * d;
      }
  red[tid] = local;
  __syncthreads();
  for (int s = 128; s > 0; s >>= 1) {
    if (tid < s) red[tid] += red[tid + s];
    __syncthreads();
  }
  if (tid == 0) atomicAdd(el_accum, red[0]);
}

// ---------------- persistent GRU: line-granular flag dataflow ----------------
__device__ inline float wred64(float v) {
#pragma unroll
  for (int o = 32; o; o >>= 1) v += __shfl_xor(v, o);
  return v;
}

// 256 blocks x 512 threads, cooperative. Wave w of block p owns column
// j = p*8+w; its 3 w_hh rows live in registers (lane-strided k).
// State layout hsx[s][p][b][8]: block p's per-step output is EXACTLY one
// 128 B line -> line-granular validity. Producer: agent write-through
// stores + __syncthreads (vmcnt drain) + per-block flag (monotone s+1).
// Consumer thread t: polls ONLY flag[t>>1] (4 B agent load), then restages
// its 16 floats with plain cached float4 loads — addresses fresh each step
// (no stale lines), line owned by one producer (no partial-line hazard).
// Restage of fast producers overlaps waiting for stragglers.
__global__ __launch_bounds__(512, 2) void gru_persistent(
    const float* __restrict__ xi,    // [B,S,3GH]
    const float* __restrict__ w_hh,  // [3GH,GH]
    const float* __restrict__ hn,    // [B,GH]
    float* __restrict__ hsx,         // [S][256][4][8]
    int* __restrict__ flags) {       // [256*FPAD], zeroed
  __shared__ __align__(16) float hsm[BB * GH];  // [k][b] interleaved, 32 KB
  const int tid = threadIdx.x;
  const int wave = tid >> 6, lane = tid & 63;
  const int j = blockIdx.x * 8 + wave;

  float wgr[32], wgz[32], wgn[32];
  {
    const float* pr = w_hh + (size_t)j * GH;
    const float* pz = w_hh + (size_t)(GH + j) * GH;
    const float* pn = w_hh + (size_t)(2 * GH + j) * GH;
#pragma unroll
    for (int c = 0; c < 32; ++c) {
      int k = c * 64 + lane;
      wgr[c] = pr[k]; wgz[c] = pz[k]; wgn[c] = pn[k];
    }
  }
#pragma unroll
  for (int i = 0; i < 4; ++i) {
    int k = tid + i * 512;
    float4 v;
    v.x = hn[0 * GH + k]; v.y = hn[1 * GH + k];
    v.z = hn[2 * GH + k]; v.w = hn[3 * GH + k];
    *(float4*)(&hsm[k * 4]) = v;
  }
  __syncthreads();

  for (int s = 0; s < SS; ++s) {
    float xr = 0.f, xz = 0.f, xn_ = 0.f;
    if (lane < BB) {
      const float* xrow = xi + ((size_t)(lane * SS + s)) * G3;
      xr  = xrow[j];
      xz  = xrow[GH + j];
      xn_ = xrow[2 * GH + j];
    }

    float ar[BB] = {}, az[BB] = {}, an[BB] = {};
#pragma unroll
    for (int c = 0; c < 32; ++c) {
      float4 h4 = *(const float4*)(&hsm[(c * 64 + lane) * 4]);
      float w_r = wgr[c], w_z = wgz[c], w_n = wgn[c];
      ar[0] = fmaf(w_r, h4.x, ar[0]); az[0] = fmaf(w_z, h4.x, az[0]); an[0] = fmaf(w_n, h4.x, an[0]);
      ar[1] = fmaf(w_r, h4.y, ar[1]); az[1] = fmaf(w_z, h4.y, az[1]); an[1] = fmaf(w_n, h4.y, an[1]);
      ar[2] = fmaf(w_r, h4.z, ar[2]); az[2] = fmaf(w_z, h4.z, az[2]); an[2] = fmaf(w_n, h4.z, an[2]);
      ar[3] = fmaf(w_r, h4.w, ar[3]); az[3] = fmaf(w_z, h4.w, az[3]); an[3] = fmaf(w_n, h4.w, an[3]);
    }
#pragma unroll
    for (int b = 0; b < BB; ++b) { ar[b] = wred64(ar[b]); az[b] = wred64(az[b]); an[b] = wred64(an[b]); }

    if (lane < BB) {
      const int b = lane;
      float r = 1.0f / (1.0f + expf(-(xr + ar[b])));
      float z = 1.0f / (1.0f + expf(-(xz + az[b])));
      float n = tanhf(xn_ + r * an[b]);
      float hp = hsm[j * 4 + b];
      float hv = (1.0f - z) * n + z * hp;
      // write-through store (agent scope): visible at L3, no fence needed
      __hip_atomic_store(hsx + (((size_t)s * 256 + blockIdx.x) * BB + b) * 8 + (j & 7),
                         hv, __ATOMIC_RELAXED, __HIP_MEMORY_SCOPE_AGENT);
    }

    if (s + 1 < SS) {
      __syncthreads();  // drains vmcnt: this block's h stores are at L3
      if (tid == 0)
        __hip_atomic_store(&flags[blockIdx.x * FPAD], s + 1,
                           __ATOMIC_RELAXED, __HIP_MEMORY_SCOPE_AGENT);
      // per-thread: cols 4t..4t+3 live in producer block t>>1's 128B line
      const int p = tid >> 1;
      const int c4 = (tid & 1) * 4;
      const int want = s + 1;
      while (__hip_atomic_load(&flags[p * FPAD], __ATOMIC_RELAXED,
                               __HIP_MEMORY_SCOPE_AGENT) < want)
        __builtin_amdgcn_s_sleep(1);
      const float* line = hsx + ((size_t)s * 256 + p) * 32 + c4;
      float4 v0 = *(const float4*)(line + 0 * 8);
      float4 v1 = *(const float4*)(line + 1 * 8);
      float4 v2 = *(const float4*)(line + 2 * 8);
      float4 v3 = *(const float4*)(line + 3 * 8);
      const int k0 = tid * 4;
      *(float4*)(&hsm[(k0 + 0) * 4]) = float4{v0.x, v1.x, v2.x, v3.x};
      *(float4*)(&hsm[(k0 + 1) * 4]) = float4{v0.y, v1.y, v2.y, v3.y};
      *(float4*)(&hsm[(k0 + 2) * 4]) = float4{v0.z, v1.z, v2.z, v3.z};
      *(float4*)(&hsm[(k0 + 3) * 4]) = float4{v0.w, v1.w, v2.w, v3.w};
      __syncthreads();  // hsm fully restaged before next dot
    }
  }
}

// ---------------- per-token: normalize, gram/speciality, cosine --------------
__device__ inline float red16(float v) {
#pragma unroll
  for (int o = 8; o; o >>= 1) v += __shfl_xor(v, o);
  return v;
}

__global__ __launch_bounds__(256) void token_kernel(const float* __restrict__ hsx,
                                                    const float* __restrict__ expr,
                                                    float* __restrict__ cos_out,
                                                    float* __restrict__ sp_accum) {
  __shared__ float routn[EE * 132];
  __shared__ float rowc[EE];
  const int t = blockIdx.x;           // b*S + s
  const int b = t / SS, s = t % SS;
  const int tid = threadIdx.x;
  const int e = tid >> 4, sub = tid & 15;

  // k = e*128 + sub*8 + i  ->  hsx[(s*256 + (k>>3))*32 + b*8 + (k&7)]
  const float* rrow = hsx + ((size_t)s * 256 + e * 16 + sub) * 32 + b * 8;
  float rv[8];
  *(float4*)(rv)     = *(const float4*)(rrow);
  *(float4*)(rv + 4) = *(const float4*)(rrow + 4);
  float ss = 0.f;
#pragma unroll
  for (int i = 0; i < 8; ++i) ss += rv[i] * rv[i];
  ss = red16(ss);
  float inv = 1.0f / fmaxf(sqrtf(ss), 1e-12f);
#pragma unroll
  for (int i = 0; i < 8; ++i) {
    rv[i] *= inv;
    routn[e * 132 + sub * 8 + i] = rv[i];
  }

  const float* erow = expr + (size_t)t * GH + e * DD + sub * 8;
  float en2 = 0.f, dot = 0.f;
#pragma unroll
  for (int i = 0; i < 8; ++i) {
    float ev = erow[i];
    en2 += ev * ev;
    dot += ev * rv[i];
  }
  en2 = red16(en2);
  dot = red16(dot);
  if (sub == 0) {
    float cosv = dot / fmaxf(sqrtf(en2), 1e-8f);
    cos_out[t * EE + e] = 1.0f - cosv;
  }
  __syncthreads();

  const int f = sub;
  float g = 0.f;
#pragma unroll
  for (int d = 0; d < DD; ++d)
    g = fmaf(routn[e * 132 + d], routn[f * 132 + d], g);
  float diff = g - ((e == f) ? 1.0f : 0.0f);
  float rowsum = red16(diff * diff);
  if (f == 0) {
    float nrm = fmaxf(sqrtf(rowsum), 1e-12f);
    rowc[e] = rowsum / (nrm * nrm);
  }
  __syncthreads();
  if (tid == 0) {
    float tok = 0.f;
#pragma unroll
    for (int i = 0; i < EE; ++i) tok += rowc[i];
    atomicAdd(sp_accum, tok);
  }
}

// ---------------- final: top-2 + softmax + EMA adjust + hn copy + scalars ----
__global__ __launch_bounds__(256) void final_kernel(const float* __restrict__ hsx,
                                                    const float* __restrict__ cos_out,
                                                    const float* __restrict__ ema,
                                                    const float* __restrict__ accum,
                                                    float* __restrict__ out_mult,
                                                    float* __restrict__ out_sel,
                                                    float* __restrict__ out_hn,
                                                    float* __restrict__ out_sp,
                                                    float* __restrict__ out_el) {
  const int gtid = blockIdx.x * 256 + threadIdx.x;
  if (gtid < BB * GH) {
    int b = gtid / GH, k = gtid % GH;
    out_hn[gtid] = hsx[((size_t)(SS - 1) * 256 + (k >> 3)) * 32 + b * 8 + (k & 7)];
  }
  if (gtid < NTOK) {
    float sp = accum[0] / (float)NTOK;
    float scale = 1.0f + sp;
    float dv[EE];
#pragma unroll
    for (int e = 0; e < EE; ++e) dv[e] = cos_out[gtid * EE + e] * scale;
    int i0 = 0; float v0 = dv[0];
#pragma unroll
    for (int e = 1; e < EE; ++e) { if (dv[e] > v0) { v0 = dv[e]; i0 = e; } }
    int i1 = -1; float v1 = -1e30f;
#pragma unroll
    for (int e = 0; e < EE; ++e) { if (e != i0 && dv[e] > v1) { v1 = dv[e]; i1 = e; } }
    float ex = expf(v1 - v0);
    float den = 1.0f + ex;
    float m0 = 1.0f / den, m1 = ex / den;
    float total = 0.f;
#pragma unroll
    for (int e = 0; e < EE; ++e) total += ema[e];
    float a0 = 0.f, a1 = 0.f;
    if (total > 0.f) {
      float invt = 1.0f / fmaxf(total, 1e-12f);
      a0 = ema[i0] * invt * 0.01f * (float)EE;
      a1 = ema[i1] * invt * 0.01f * (float)EE;
    }
    out_mult[gtid * 2 + 0] = m0 - a0;
    out_mult[gtid * 2 + 1] = m1 - a1;
    out_sel[gtid * 2 + 0] = (float)i0;
    out_sel[gtid * 2 + 1] = (float)i1;
  }
  if (gtid == 0) {
    out_sp[0] = accum[0] / (float)NTOK;
    out_el[0] = accum[1] / (float)(GH * GH);
  }
}

extern "C" void kernel_launch(void* const* d_in, const int* in_sizes, int n_in,
                              void* d_out, int out_size, void* d_ws, size_t ws_size,
                              hipStream_t stream) {
  const float* x      = (const float*)d_in[0];  // [B,S,H]
  const float* hn     = (const float*)d_in[1];  // [1,B,GH]
  const float* w_ih   = (const float*)d_in[2];  // [3GH,H]
  const float* w_hh   = (const float*)d_in[3];  // [3GH,GH]
  const float* w_expr = (const float*)d_in[4];  // [H,GH]
  const float* ema    = (const float*)d_in[5];  // [E]
  float* out = (float*)d_out;

  float* out_mult = out;                 // 4096
  float* out_sel  = out + 4096;          // 4096
  float* out_expr = out + 8192;          // 4194304
  float* out_hn   = out + 4202496;       // 8192
  float* out_sp   = out + 4210688;       // 1
  float* out_cos  = out + 4210689;       // 32768
  float* out_el   = out + 4243457;       // 1

  float* ws = (float*)d_ws;
  float* xi    = ws;                      // 12,582,912 floats
  float* hsx   = ws + 12582912;           // [S][256][4][8] = 4,194,304 floats
  float* accum = ws + 16777216;           // [0]=sp_sum, [1]=el_sum
  int*   flags = (int*)(ws + 16777220);   // 256*FPAD ints
  // bf16 split arrays (guarded by ws_size)
  unsigned short* xh  = (unsigned short*)(ws + 16785920);  // 4.2M shorts
  unsigned short* xl  = (unsigned short*)(ws + 18883072);
  unsigned short* wth = (unsigned short*)(ws + 20980224);  // w_exprT hi
  unsigned short* wtl = (unsigned short*)(ws + 23077376);
  const size_t need_bytes = (size_t)25174528 * 4;
  const bool bf16path = ws_size >= need_bytes;

  hipMemsetAsync(accum, 0, (4 + 256 * FPAD) * sizeof(float), stream);

  // xi = x @ w_ih^T (fp32 — feeds chaotic recurrence)
  gemm_abt<<<dim3(G3 / 128, NTOK / 128), 256, 0, stream>>>(x, w_ih, xi, NTOK, G3, HH);

  if (bf16path) {
    split_mat<<<4096, 256, 0, stream>>>(x, xh, xl, NTOK * HH);
    transpose_split<<<dim3(GH / 64, HH / 64), 256, 0, stream>>>(w_expr, wth, wtl);
    // expression_logits = x @ w_expr = x * (w_exprT)^T
    gemm_abt_bf16<<<dim3(GH / 128, NTOK / 128), 256, 0, stream>>>(
        xh, xl, wth, wtl, out_expr, NTOK, GH, HH);
    // expression loss: (w_exprT * w_exprT^T - I)^2 mean
    ata_bf16<<<dim3(GH / 128, GH / 128), 256, 0, stream>>>(wth, wtl, accum + 1, GH, HH);
  } else {
    gemm_ab<<<dim3(GH / 128, NTOK / 128), 256, 0, stream>>>(x, w_expr, out_expr, NTOK, GH, HH);
    ata_loss<<<dim3(GH / 128, GH / 128), 256, 0, stream>>>(w_expr, accum + 1, GH, HH);
  }

  // GRU recurrence: persistent cooperative kernel, line-granular flags
  {
    void* args[] = {(void*)&xi, (void*)&w_hh, (void*)&hn, (void*)&hsx, (void*)&flags};
    hipLaunchCooperativeKernel((void*)gru_persistent, dim3(256), dim3(512),
                               args, 0, stream);
  }

  token_kernel<<<NTOK, 256, 0, stream>>>(hsx, out_expr, out_cos, accum);

  final_kernel<<<(BB * GH + 255) / 256, 256, 0, stream>>>(hsx, out_cos, ema, accum,
                                                          out_mult, out_sel, out_hn,
                                                          out_sp, out_el);
}